// Round 6
// baseline (138.256 us; speedup 1.0000x reference)
//
#include <hip/hip_runtime.h>

// Multi-scale deformable attention forward.
// value:              (N, Lin, nH, D)        float32
// spatial_shapes:     (L, 2)                 int32/int64 (runtime-detected)
// level_start_index:  (L,)                   int32/int64 (runtime-detected)
// sampling_locations: (N, Lq, nH, L, P, 2)   float32
// attention_weights:  (N, Lq, nH, L, P)      float32
// out:                (N, Lq, nH*D)          float32
#define NH 8
#define DD 32
#define LL 4
#define PP 4

typedef float  f32x4  __attribute__((ext_vector_type(4)));
typedef float  f32x2  __attribute__((ext_vector_type(2)));
typedef int    i32x4  __attribute__((ext_vector_type(4)));
typedef _Float16 half8 __attribute__((ext_vector_type(8)));
typedef _Float16 half4v __attribute__((ext_vector_type(4)));

// ---------------- prepass: value (n,pos,h,d) fp32 -> (n,h,pos,d) fp16 ----------------
__global__ __launch_bounds__(256) void conv_kernel(
    const float* __restrict__ value, _Float16* __restrict__ vh,
    int Lin, int total)
{
    int tid = blockIdx.x * blockDim.x + threadIdx.x;
    if (tid >= total) return;
    const int d4  = tid & 7;
    const int pos = (tid >> 3) % Lin;
    const int nh  = tid / (8 * Lin);
    const int n   = nh >> 3;
    const int h   = nh & 7;

    const f32x4 v = *(const f32x4*)(value + (((size_t)n * Lin + pos) * NH + h) * DD + d4 * 4);
    half4v o;
    o.x = (_Float16)v.x; o.y = (_Float16)v.y; o.z = (_Float16)v.z; o.w = (_Float16)v.w;
    *(half4v*)(vh + ((size_t)nh * Lin + pos) * DD + d4 * 4) = o;
}

// ---------------- main kernel ----------------
// Block = one (n,h) slab x 32 queries; blockIdx%8 -> XCD so each XCD's L2
// holds only 2 slabs (1.44 MB) -> gathers stay L2-hit (R4: FETCH at stream floor).
//
// Phase 1: coordinate math once per (unit,point): thread (u,j) computes points
// 2j,2j+1 (both x-sides) -> 4 LDS entries {off_top,off_bot,w_top,w_bot}.
// LDS layout: idx = 41*u + 5*j + 2*pt + e  (unit stride 41, writer stride 5:
// write quads (u+5j)%8 spread 2-per-quad -> free; R5's [u][k] layout was 4-way).
// Phase 2: lane j (side=j>>2, cg=j&3) per point: 1 ds_read_b128 +
// 2 saddr global_load_dwordx4 + 16 fma_mix, double-buffered in 4-point batches.
// waves_per_eu(4) min-only: R5's max=4 cap held occupancy to 34%.
__global__ __attribute__((amdgpu_flat_work_group_size(256, 256)))
__attribute__((amdgpu_waves_per_eu(4)))
void msda_fwd_h(
    const _Float16* __restrict__ vh,
    const int*   __restrict__ ssh,
    const int*   __restrict__ lsi,
    const float* __restrict__ sloc,
    const float* __restrict__ aw,
    float*       __restrict__ out,
    int N, int Lq, int Lin, int spx, int nSlabs)
{
    __shared__ i32x4 ent[32 * 41];   // 21 KB

    const int xcd   = blockIdx.x & 7;
    const int blk   = blockIdx.x >> 3;
    const int sw    = blk % spx;
    const int chunk = blk / spx;
    const int slab  = xcd * spx + sw;          // n*NH + h  (block-uniform)
    if (slab >= nSlabs) return;                // uniform -> barrier-safe

    const int t  = threadIdx.x;
    const int u  = t >> 3;                     // unit (query) within block
    const int j  = t & 7;
    const int q  = chunk * 32 + u;
    const int qc = min(q, Lq - 1);
    const int n  = slab >> 3;
    const int h  = slab & 7;

    // ---- phase 1: points p = 2j, 2j+1 of unit u (both sides) ----
    {
        const size_t nqh = ((size_t)n * Lq + qc) * NH + h;
        const int l = j >> 1;                  // both points share a level
        const bool is64 = (ssh[1] == 0);
        const int W = is64 ? ssh[4 * l + 2] : ssh[2 * l + 1];
        const int H = is64 ? ssh[4 * l]     : ssh[2 * l];
        const int S = is64 ? lsi[2 * l]     : lsi[l];
        const f32x4 lc = __builtin_nontemporal_load((const f32x4*)sloc + nqh * 8 + j);
        const f32x2 av = __builtin_nontemporal_load((const f32x2*)aw + nqh * 8 + j);
        const float fW = (float)W, fH = (float)H;
        const int rowb  = W * (DD * 2);
        const int sbase = S * (DD * 2);
#pragma unroll
        for (int pt = 0; pt < 2; ++pt) {
            const float x  = lc[2 * pt]     * fW - 0.5f;
            const float y  = lc[2 * pt + 1] * fH - 0.5f;
            const float wq = av[pt];
            const float x0f = floorf(x), y0f = floorf(y);
            const int x0 = (int)x0f, y0 = (int)y0f;
            const float dx = x - x0f, dy = y - y0f;
            const int x1 = x0 + 1, y1 = y0 + 1;
            const bool vx0 = (x0 >= 0) & (x0 < W), vx1 = (x1 >= 0) & (x1 < W);
            const bool vy0 = (y0 >= 0) & (y0 < H), vy1 = (y1 >= 0) & (y1 < H);
            const int cx0 = min(max(x0, 0), W - 1), cx1 = min(max(x1, 0), W - 1);
            const int cy0 = min(max(y0, 0), H - 1), cy1 = min(max(y1, 0), H - 1);
            const float wx0 = (1.f - dx) * wq * (vx0 ? 1.f : 0.f);
            const float wx1 = dx         * wq * (vx1 ? 1.f : 0.f);
            const float ty  = (1.f - dy) * (vy0 ? 1.f : 0.f);
            const float by  = dy         * (vy1 ? 1.f : 0.f);
            const int rt = cy0 * rowb + sbase;
            const int rb = cy1 * rowb + sbase;
            i32x4 e0, e1;
            e0.x = rt + cx0 * (DD * 2);  e0.y = rb + cx0 * (DD * 2);
            e0.z = __float_as_int(wx0 * ty);  e0.w = __float_as_int(wx0 * by);
            e1.x = rt + cx1 * (DD * 2);  e1.y = rb + cx1 * (DD * 2);
            e1.z = __float_as_int(wx1 * ty);  e1.w = __float_as_int(wx1 * by);
            const int base = u * 41 + 5 * j + 2 * pt;
            ent[base]     = e0;
            ent[base + 1] = e1;
        }
    }
    __syncthreads();
    if (q >= Lq) return;

    // ---- phase 2 ----
    const int side = j >> 2;
    const int cg   = j & 3;
    const int cg16 = cg * 16;                   // byte offset of channel group
    const char* __restrict__ sb =
        (const char*)vh + (size_t)slab * Lin * (DD * 2);   // scalar base -> saddr loads
    const int ub = u * 41 + side;

    float acc[8];
#pragma unroll
    for (int k = 0; k < 8; ++k) acc[k] = 0.f;

    // entry for point p=4b+i: idx = ub + 10b + {0,2,5,7}[i]
#define RD(b, E) { \
    E[0] = ent[ub + 10 * (b) + 0]; \
    E[1] = ent[ub + 10 * (b) + 2]; \
    E[2] = ent[ub + 10 * (b) + 5]; \
    E[3] = ent[ub + 10 * (b) + 7]; }
#define LD(E, V) _Pragma("unroll") \
    for (int i = 0; i < 4; ++i) { \
        V[2*i]   = *(const half8*)(sb + (unsigned)(E[i].x + cg16)); \
        V[2*i+1] = *(const half8*)(sb + (unsigned)(E[i].y + cg16)); }
#define AC(E, V) _Pragma("unroll") \
    for (int i = 0; i < 4; ++i) { \
        const float wt = __int_as_float(E[i].z); \
        const float wb = __int_as_float(E[i].w); \
        _Pragma("unroll") for (int ch = 0; ch < 8; ++ch) \
            acc[ch] = fmaf((float)V[2*i][ch], wt, fmaf((float)V[2*i+1][ch], wb, acc[ch])); }

    i32x4 E0[4], E1[4], E2[4], E3[4];
    half8 V0[8], V1[8], V2[8], V3[8];
    RD(0, E0) LD(E0, V0)
    RD(1, E1) LD(E1, V1)
    AC(E0, V0)
    RD(2, E2) LD(E2, V2)
    AC(E1, V1)
    RD(3, E3) LD(E3, V3)
    AC(E2, V2)
    AC(E3, V3)

    // merge x0/x1 partials: partner lane is j ^ 4
#pragma unroll
    for (int k = 0; k < 8; ++k)
        acc[k] += __shfl_xor(acc[k], 4);

    f32x4 st;
    st.x = acc[side * 4 + 0];
    st.y = acc[side * 4 + 1];
    st.z = acc[side * 4 + 2];
    st.w = acc[side * 4 + 3];
    const size_t onqh = ((size_t)n * Lq + q) * NH + h;
    __builtin_nontemporal_store(st, (f32x4*)(out + onqh * DD + cg * 8 + side * 4));
}

// ---------------- fp32 fallback if ws too small ----------------
__global__ __launch_bounds__(256) void msda_fwd_f32(
    const float* __restrict__ value,
    const int*   __restrict__ spatial_shapes,
    const int*   __restrict__ level_start,
    const float* __restrict__ sloc,
    const float* __restrict__ aw,
    float*       __restrict__ out,
    int N, int Lq, int Lin, int total)
{
    int tid = blockIdx.x * blockDim.x + threadIdx.x;
    if (tid >= total) return;
    const int c  = tid & 7;
    const int h  = (tid >> 3) & 7;
    const int nq = tid >> 6;
    const int n  = nq / Lq;
    const bool is64 = (spatial_shapes[1] == 0);
    int Hs[LL], Ws[LL], Ss[LL];
#pragma unroll
    for (int l = 0; l < LL; ++l) {
        if (is64) { Hs[l] = spatial_shapes[4*l]; Ws[l] = spatial_shapes[4*l+2]; Ss[l] = level_start[2*l]; }
        else      { Hs[l] = spatial_shapes[2*l]; Ws[l] = spatial_shapes[2*l+1]; Ss[l] = level_start[l]; }
    }
    const size_t nqh = (size_t)nq * NH + h;
    const float* loc_p = sloc + nqh * (LL * PP * 2);
    const float* aw_p  = aw   + nqh * (LL * PP);
    float4 acc = make_float4(0.f, 0.f, 0.f, 0.f);
#pragma unroll
    for (int l = 0; l < LL; ++l) {
        const int H = Hs[l], W = Ws[l];
        const float* vb = value + (((size_t)n * Lin + Ss[l]) * NH + h) * DD + c * 4;
#pragma unroll
        for (int p = 0; p < PP; ++p) {
            const int jj = l * PP + p;
            const float x = loc_p[2*jj] * (float)W - 0.5f;
            const float y = loc_p[2*jj+1] * (float)H - 0.5f;
            const float w = aw_p[jj];
            const float x0f = floorf(x), y0f = floorf(y);
            const int x0 = (int)x0f, y0 = (int)y0f, x1 = x0+1, y1 = y0+1;
            const float dx = x - x0f, dy = y - y0f;
            const bool vx0 = x0>=0 && x0<W, vx1 = x1>=0 && x1<W;
            const bool vy0 = y0>=0 && y0<H, vy1 = y1>=0 && y1<H;
            const int cx0 = min(max(x0,0),W-1), cx1 = min(max(x1,0),W-1);
            const int cy0 = min(max(y0,0),H-1), cy1 = min(max(y1,0),H-1);
            const float w00 = (1.f-dx)*(1.f-dy)*w*((vx0&&vy0)?1.f:0.f);
            const float w01 = dx*(1.f-dy)*w*((vx1&&vy0)?1.f:0.f);
            const float w10 = (1.f-dx)*dy*w*((vx0&&vy1)?1.f:0.f);
            const float w11 = dx*dy*w*((vx1&&vy1)?1.f:0.f);
            const float4 v00 = *(const float4*)(vb + (size_t)(cy0*W+cx0)*(NH*DD));
            const float4 v01 = *(const float4*)(vb + (size_t)(cy0*W+cx1)*(NH*DD));
            const float4 v10 = *(const float4*)(vb + (size_t)(cy1*W+cx0)*(NH*DD));
            const float4 v11 = *(const float4*)(vb + (size_t)(cy1*W+cx1)*(NH*DD));
            acc.x += w00*v00.x + w01*v01.x + w10*v10.x + w11*v11.x;
            acc.y += w00*v00.y + w01*v01.y + w10*v10.y + w11*v11.y;
            acc.z += w00*v00.z + w01*v01.z + w10*v10.z + w11*v11.z;
            acc.w += w00*v00.w + w01*v01.w + w10*v10.w + w11*v11.w;
        }
    }
    *(float4*)(out + nqh * DD + c * 4) = acc;
}

extern "C" void kernel_launch(void* const* d_in, const int* in_sizes, int n_in,
                              void* d_out, int out_size, void* d_ws, size_t ws_size,
                              hipStream_t stream)
{
    const float* value = (const float*)d_in[0];
    const int*   ss    = (const int*)  d_in[1];
    const int*   lsi   = (const int*)  d_in[2];
    const float* sloc  = (const float*)d_in[3];
    const float* aw    = (const float*)d_in[4];
    float* out = (float*)d_out;

    const int N = 2;
    const int Lq  = in_sizes[4] / (N * NH * LL * PP);
    const int Lin = in_sizes[0] / (N * NH * DD);

    const size_t need = (size_t)N * NH * Lin * DD * sizeof(_Float16);
    if (ws_size >= need) {
        _Float16* vh = (_Float16*)d_ws;
        const int ctotal = N * NH * Lin * 8;
        conv_kernel<<<(ctotal + 255) / 256, 256, 0, stream>>>(value, vh, Lin, ctotal);

        const int nSlabs = N * NH;              // 16
        const int spx    = (nSlabs + 7) / 8;    // slabs per XCD = 2
        const int chunks = (Lq + 31) / 32;
        const int grid   = 8 * spx * chunks;
        msda_fwd_h<<<grid, 256, 0, stream>>>(vh, ss, lsi, sloc, aw, out,
                                             N, Lq, Lin, spx, nSlabs);
    } else {
        const int total = N * Lq * NH * 8;
        msda_fwd_f32<<<(total + 255) / 256, 256, 0, stream>>>(value, ss, lsi, sloc, aw, out,
                                                              N, Lq, Lin, total);
    }
}

// Round 7
// 135.006 us; speedup vs baseline: 1.0241x; 1.0241x over previous
//
#include <hip/hip_runtime.h>

// Multi-scale deformable attention forward.
// value:              (N, Lin, nH, D)        float32
// spatial_shapes:     (L, 2)                 int32/int64 (runtime-detected)
// level_start_index:  (L,)                   int32/int64 (runtime-detected)
// sampling_locations: (N, Lq, nH, L, P, 2)   float32
// attention_weights:  (N, Lq, nH, L, P)      float32
// out:                (N, Lq, nH*D)          float32
#define NH 8
#define DD 32
#define LL 4
#define PP 4

typedef float  f32x4  __attribute__((ext_vector_type(4)));
typedef float  f32x2  __attribute__((ext_vector_type(2)));
typedef int    i32x4  __attribute__((ext_vector_type(4)));
typedef _Float16 half4v __attribute__((ext_vector_type(4)));

// ---------------- prepass: value (n,pos,h,d) fp32 -> (n,h,pos,d) fp16 ----------------
__global__ __launch_bounds__(256) void conv_kernel(
    const float* __restrict__ value, _Float16* __restrict__ vh,
    int Lin, int total)
{
    int tid = blockIdx.x * blockDim.x + threadIdx.x;
    if (tid >= total) return;
    const int d4  = tid & 7;
    const int pos = (tid >> 3) % Lin;
    const int nh  = tid / (8 * Lin);
    const int n   = nh >> 3;
    const int h   = nh & 7;

    const f32x4 v = *(const f32x4*)(value + (((size_t)n * Lin + pos) * NH + h) * DD + d4 * 4);
    half4v o;
    o.x = (_Float16)v.x; o.y = (_Float16)v.y; o.z = (_Float16)v.z; o.w = (_Float16)v.w;
    *(half4v*)(vh + ((size_t)nh * Lin + pos) * DD + d4 * 4) = o;
}

// acc(f32) += f16(lo/hi half of DW) * W(f32)  — single v_fma_mix_f32.
// op_sel_hi[0]=1 -> src0 is f16; op_sel[0] picks lo(0)/hi(1) half.
#define FMAMIX_LO(ACC, DW, W) \
    asm("v_fma_mix_f32 %0, %1, %2, %0 op_sel:[0,0,0] op_sel_hi:[1,0,0]" \
        : "+v"(ACC) : "v"(DW), "v"(W))
#define FMAMIX_HI(ACC, DW, W) \
    asm("v_fma_mix_f32 %0, %1, %2, %0 op_sel:[1,0,0] op_sel_hi:[1,0,0]" \
        : "+v"(ACC) : "v"(DW), "v"(W))

// ---------------- main kernel ----------------
// Block = one (n,h) slab x 32 queries; blockIdx%8 -> XCD so each XCD's L2
// holds only 2 slabs (1.44 MB) -> gathers stay L2-hit (R4: FETCH at stream floor).
// Phase 1: coordinate math once per (unit,point) -> LDS entries
// {off_top,off_bot,w_top,w_bot}, conflict-free layout (R6: conflicts 0).
// Phase 2: lane j (side=j>>2, cg=j&3) per point: 1 ds_read_b128 +
// 2 saddr global_load_dwordx4 + 16 v_fma_mix_f32 (asm — R6 showed the
// compiler's half->float chains cost ~2.4x the fma_mix floor).
__global__ __attribute__((amdgpu_flat_work_group_size(256, 256)))
__attribute__((amdgpu_waves_per_eu(4)))
void msda_fwd_h(
    const _Float16* __restrict__ vh,
    const int*   __restrict__ ssh,
    const int*   __restrict__ lsi,
    const float* __restrict__ sloc,
    const float* __restrict__ aw,
    float*       __restrict__ out,
    int N, int Lq, int Lin, int spx, int nSlabs)
{
    __shared__ i32x4 ent[32 * 41];   // 21 KB

    const int xcd   = blockIdx.x & 7;
    const int blk   = blockIdx.x >> 3;
    const int sw    = blk % spx;
    const int chunk = blk / spx;
    const int slab  = xcd * spx + sw;          // n*NH + h  (block-uniform)
    if (slab >= nSlabs) return;                // uniform -> barrier-safe

    const int t  = threadIdx.x;
    const int u  = t >> 3;                     // unit (query) within block
    const int j  = t & 7;
    const int q  = chunk * 32 + u;
    const int qc = min(q, Lq - 1);
    const int n  = slab >> 3;
    const int h  = slab & 7;

    // ---- phase 1: points p = 2j, 2j+1 of unit u (both sides) ----
    {
        const size_t nqh = ((size_t)n * Lq + qc) * NH + h;
        const int l = j >> 1;                  // both points share a level
        const bool is64 = (ssh[1] == 0);
        const int W = is64 ? ssh[4 * l + 2] : ssh[2 * l + 1];
        const int H = is64 ? ssh[4 * l]     : ssh[2 * l];
        const int S = is64 ? lsi[2 * l]     : lsi[l];
        const f32x4 lc = __builtin_nontemporal_load((const f32x4*)sloc + nqh * 8 + j);
        const f32x2 av = __builtin_nontemporal_load((const f32x2*)aw + nqh * 8 + j);
        const float fW = (float)W, fH = (float)H;
        const int rowb  = W * (DD * 2);
        const int sbase = S * (DD * 2);
#pragma unroll
        for (int pt = 0; pt < 2; ++pt) {
            const float x  = lc[2 * pt]     * fW - 0.5f;
            const float y  = lc[2 * pt + 1] * fH - 0.5f;
            const float wq = av[pt];
            const float x0f = floorf(x), y0f = floorf(y);
            const int x0 = (int)x0f, y0 = (int)y0f;
            const float dx = x - x0f, dy = y - y0f;
            const int x1 = x0 + 1, y1 = y0 + 1;
            const bool vx0 = (x0 >= 0) & (x0 < W), vx1 = (x1 >= 0) & (x1 < W);
            const bool vy0 = (y0 >= 0) & (y0 < H), vy1 = (y1 >= 0) & (y1 < H);
            const int cx0 = min(max(x0, 0), W - 1), cx1 = min(max(x1, 0), W - 1);
            const int cy0 = min(max(y0, 0), H - 1), cy1 = min(max(y1, 0), H - 1);
            const float wx0 = (1.f - dx) * wq * (vx0 ? 1.f : 0.f);
            const float wx1 = dx         * wq * (vx1 ? 1.f : 0.f);
            const float ty  = (1.f - dy) * (vy0 ? 1.f : 0.f);
            const float by  = dy         * (vy1 ? 1.f : 0.f);
            const int rt = cy0 * rowb + sbase;
            const int rb = cy1 * rowb + sbase;
            i32x4 e0, e1;
            e0.x = rt + cx0 * (DD * 2);  e0.y = rb + cx0 * (DD * 2);
            e0.z = __float_as_int(wx0 * ty);  e0.w = __float_as_int(wx0 * by);
            e1.x = rt + cx1 * (DD * 2);  e1.y = rb + cx1 * (DD * 2);
            e1.z = __float_as_int(wx1 * ty);  e1.w = __float_as_int(wx1 * by);
            const int base = u * 41 + 5 * j + 2 * pt;
            ent[base]     = e0;
            ent[base + 1] = e1;
        }
    }
    __syncthreads();
    if (q >= Lq) return;

    // ---- phase 2 ----
    const int side = j >> 2;
    const int cg   = j & 3;
    const char* __restrict__ sb =
        (const char*)vh + (size_t)slab * Lin * (DD * 2) + cg * 16;  // saddr + lane base
    const int ub = u * 41 + side;

    float acc[8];
#pragma unroll
    for (int k = 0; k < 8; ++k) acc[k] = 0.f;

    // entry for point p=4b+i: idx = ub + 10b + {0,2,5,7}[i]
#define RD(b, E) { \
    E[0] = ent[ub + 10 * (b) + 0]; \
    E[1] = ent[ub + 10 * (b) + 2]; \
    E[2] = ent[ub + 10 * (b) + 5]; \
    E[3] = ent[ub + 10 * (b) + 7]; }
#define LD(E, V) _Pragma("unroll") \
    for (int i = 0; i < 4; ++i) { \
        V[2*i]   = *(const i32x4*)(sb + (unsigned)E[i].x); \
        V[2*i+1] = *(const i32x4*)(sb + (unsigned)E[i].y); }
#define AC(E, V) _Pragma("unroll") \
    for (int i = 0; i < 4; ++i) { \
        const float wt = __int_as_float(E[i].z); \
        const float wb = __int_as_float(E[i].w); \
        _Pragma("unroll") for (int d = 0; d < 4; ++d) { \
            FMAMIX_LO(acc[2*d],   V[2*i][d],   wt); \
            FMAMIX_HI(acc[2*d+1], V[2*i][d],   wt); \
            FMAMIX_LO(acc[2*d],   V[2*i+1][d], wb); \
            FMAMIX_HI(acc[2*d+1], V[2*i+1][d], wb); } }

    i32x4 E0[4], E1[4], E2[4], E3[4];
    i32x4 V0[8], V1[8], V2[8], V3[8];
    RD(0, E0) LD(E0, V0)
    RD(1, E1) LD(E1, V1)
    AC(E0, V0)
    RD(2, E2) LD(E2, V2)
    AC(E1, V1)
    RD(3, E3) LD(E3, V3)
    AC(E2, V2)
    AC(E3, V3)

    // merge x0/x1 partials: partner lane is j ^ 4
#pragma unroll
    for (int k = 0; k < 8; ++k)
        acc[k] += __shfl_xor(acc[k], 4);

    f32x4 st;
    st.x = acc[side * 4 + 0];
    st.y = acc[side * 4 + 1];
    st.z = acc[side * 4 + 2];
    st.w = acc[side * 4 + 3];
    const size_t onqh = ((size_t)n * Lq + q) * NH + h;
    __builtin_nontemporal_store(st, (f32x4*)(out + onqh * DD + cg * 8 + side * 4));
}

// ---------------- fp32 fallback if ws too small ----------------
__global__ __launch_bounds__(256) void msda_fwd_f32(
    const float* __restrict__ value,
    const int*   __restrict__ spatial_shapes,
    const int*   __restrict__ level_start,
    const float* __restrict__ sloc,
    const float* __restrict__ aw,
    float*       __restrict__ out,
    int N, int Lq, int Lin, int total)
{
    int tid = blockIdx.x * blockDim.x + threadIdx.x;
    if (tid >= total) return;
    const int c  = tid & 7;
    const int h  = (tid >> 3) & 7;
    const int nq = tid >> 6;
    const int n  = nq / Lq;
    const bool is64 = (spatial_shapes[1] == 0);
    int Hs[LL], Ws[LL], Ss[LL];
#pragma unroll
    for (int l = 0; l < LL; ++l) {
        if (is64) { Hs[l] = spatial_shapes[4*l]; Ws[l] = spatial_shapes[4*l+2]; Ss[l] = level_start[2*l]; }
        else      { Hs[l] = spatial_shapes[2*l]; Ws[l] = spatial_shapes[2*l+1]; Ss[l] = level_start[l]; }
    }
    const size_t nqh = (size_t)nq * NH + h;
    const float* loc_p = sloc + nqh * (LL * PP * 2);
    const float* aw_p  = aw   + nqh * (LL * PP);
    float4 acc = make_float4(0.f, 0.f, 0.f, 0.f);
#pragma unroll
    for (int l = 0; l < LL; ++l) {
        const int H = Hs[l], W = Ws[l];
        const float* vb = value + (((size_t)n * Lin + Ss[l]) * NH + h) * DD + c * 4;
#pragma unroll
        for (int p = 0; p < PP; ++p) {
            const int jj = l * PP + p;
            const float x = loc_p[2*jj] * (float)W - 0.5f;
            const float y = loc_p[2*jj+1] * (float)H - 0.5f;
            const float w = aw_p[jj];
            const float x0f = floorf(x), y0f = floorf(y);
            const int x0 = (int)x0f, y0 = (int)y0f, x1 = x0+1, y1 = y0+1;
            const float dx = x - x0f, dy = y - y0f;
            const bool vx0 = x0>=0 && x0<W, vx1 = x1>=0 && x1<W;
            const bool vy0 = y0>=0 && y0<H, vy1 = y1>=0 && y1<H;
            const int cx0 = min(max(x0,0),W-1), cx1 = min(max(x1,0),W-1);
            const int cy0 = min(max(y0,0),H-1), cy1 = min(max(y1,0),H-1);
            const float w00 = (1.f-dx)*(1.f-dy)*w*((vx0&&vy0)?1.f:0.f);
            const float w01 = dx*(1.f-dy)*w*((vx1&&vy0)?1.f:0.f);
            const float w10 = (1.f-dx)*dy*w*((vx0&&vy1)?1.f:0.f);
            const float w11 = dx*dy*w*((vx1&&vy1)?1.f:0.f);
            const float4 v00 = *(const float4*)(vb + (size_t)(cy0*W+cx0)*(NH*DD));
            const float4 v01 = *(const float4*)(vb + (size_t)(cy0*W+cx1)*(NH*DD));
            const float4 v10 = *(const float4*)(vb + (size_t)(cy1*W+cx0)*(NH*DD));
            const float4 v11 = *(const float4*)(vb + (size_t)(cy1*W+cx1)*(NH*DD));
            acc.x += w00*v00.x + w01*v01.x + w10*v10.x + w11*v11.x;
            acc.y += w00*v00.y + w01*v01.y + w10*v10.y + w11*v11.y;
            acc.z += w00*v00.z + w01*v01.z + w10*v10.z + w11*v11.z;
            acc.w += w00*v00.w + w01*v01.w + w10*v10.w + w11*v11.w;
        }
    }
    *(float4*)(out + nqh * DD + c * 4) = acc;
}

extern "C" void kernel_launch(void* const* d_in, const int* in_sizes, int n_in,
                              void* d_out, int out_size, void* d_ws, size_t ws_size,
                              hipStream_t stream)
{
    const float* value = (const float*)d_in[0];
    const int*   ss    = (const int*)  d_in[1];
    const int*   lsi   = (const int*)  d_in[2];
    const float* sloc  = (const float*)d_in[3];
    const float* aw    = (const float*)d_in[4];
    float* out = (float*)d_out;

    const int N = 2;
    const int Lq  = in_sizes[4] / (N * NH * LL * PP);
    const int Lin = in_sizes[0] / (N * NH * DD);

    const size_t need = (size_t)N * NH * Lin * DD * sizeof(_Float16);
    if (ws_size >= need) {
        _Float16* vh = (_Float16*)d_ws;
        const int ctotal = N * NH * Lin * 8;
        conv_kernel<<<(ctotal + 255) / 256, 256, 0, stream>>>(value, vh, Lin, ctotal);

        const int nSlabs = N * NH;              // 16
        const int spx    = (nSlabs + 7) / 8;    // slabs per XCD = 2
        const int chunks = (Lq + 31) / 32;
        const int grid   = 8 * spx * chunks;
        msda_fwd_h<<<grid, 256, 0, stream>>>(vh, ss, lsi, sloc, aw, out,
                                             N, Lq, Lin, spx, nSlabs);
    } else {
        const int total = N * Lq * NH * 8;
        msda_fwd_f32<<<(total + 255) / 256, 256, 0, stream>>>(value, ss, lsi, sloc, aw, out,
                                                              N, Lq, Lin, total);
    }
}